// Round 8
// baseline (222.744 us; speedup 1.0000x reference)
//
#include <hip/hip_runtime.h>
#include <hip/hip_bf16.h>

typedef __hip_bfloat16 bf16;
typedef unsigned long long u64;
typedef __attribute__((ext_vector_type(8))) short short8;   // 8 bf16 = MFMA A/B frag
typedef __attribute__((ext_vector_type(4))) float f32x4;    // MFMA C/D frag

#define B_   2
#define C_   128
#define T_   32
#define N_   512
#define K_   16
#define HID_ 512
#define TN   (T_*N_)          // 16384
#define PTS  (B_*T_*N_)       // 32768

#define MFMA_BF16(a,b,c) __builtin_amdgcn_mfma_f32_16x16x32_bf16((a),(b),(c),0,0,0)

__device__ __forceinline__ float b2f(bf16 v){ return __bfloat162float(v); }
__device__ __forceinline__ bf16  f2b(float v){ return __float2bfloat16(v); }
__device__ __forceinline__ float bqf(short v){            // bf16 bits -> f32 (exact)
  return __uint_as_float(((unsigned)(unsigned short)v) << 16);
}

__device__ __forceinline__ float ldc(const void* p, int i, bool f32) {
  return f32 ? ((const float*)p)[i] : b2f(((const bf16*)p)[i]);
}

// ---------- convert weights + bn; every block locally detects input dtype; blk0 publishes flag ----------
__global__ __launch_bounds__(256) void convw_kernel(
    const void* __restrict__ x,
    const void* wq, const void* wk, const void* wv,
    const void* w1, const void* w2, const void* g, const void* bb,
    const void* m, const void* v,
    bf16* __restrict__ wqb, bf16* __restrict__ wkb, bf16* __restrict__ wvb,
    bf16* __restrict__ w1b, bf16* __restrict__ w2b,
    float* __restrict__ gf, float* __restrict__ bf_, float* __restrict__ mf,
    float* __restrict__ vf, int* __restrict__ flag)
{
  __shared__ int cnt;
  if (threadIdx.x == 0) cnt = 0;
  __syncthreads();
  const unsigned short* u = (const unsigned short*)x;
  int w = 0;
#pragma unroll
  for (int j = 0; j < 8; ++j) {
    unsigned short hv = u[threadIdx.x*8 + j];
    int e = (hv >> 7) & 0xFF;
    if (e >= 0x89) w++;
  }
  if (w) atomicAdd(&cnt, w);
  __syncthreads();
  bool f32 = (cnt > 32);
  if (blockIdx.x == 0 && threadIdx.x == 0) *flag = f32 ? 1 : 0;

  int i = blockIdx.x*256 + threadIdx.x;            // grid covers 180736 exactly
  if (i < 16384) { wqb[i] = f2b(ldc(wq, i, f32)); return; } i -= 16384;
  if (i < 16384) { wkb[i] = f2b(ldc(wk, i, f32)); return; } i -= 16384;
  if (i < 16384) { wvb[i] = f2b(ldc(wv, i, f32)); return; } i -= 16384;
  if (i < 65536) { w1b[i] = f2b(ldc(w1, i, f32)); return; } i -= 65536;
  if (i < 65536) { w2b[i] = f2b(ldc(w2, i, f32)); return; } i -= 65536;
  if (i < 128)   { gf[i]  = ldc(g, i, f32); return; }       i -= 128;
  if (i < 128)   { bf_[i] = ldc(bb, i, f32); return; }      i -= 128;
  if (i < 128)   { mf[i]  = ldc(m, i, f32); return; }       i -= 128;
  if (i < 128)   { vf[i]  = ldc(v, i, f32); return; }
}

// ---------- bitonic/shuffle helpers ----------
__device__ __forceinline__ u64 shflx64(u64 v, int m) {
  return (u64)__shfl_xor((long long)v, m, 64);
}

// ---------- MFMA GEMM helper (32-pt tile, 8 waves, wave owns one 16-col otile) ----------
__device__ __forceinline__ void proj_gemm32(const bf16* __restrict__ W,
                                            bf16 (*ys)[136],
                                            const short8 am[2][4],
                                            int mrow, int quad, int ot)
{
  f32x4 acc[2];
#pragma unroll
  for (int mt=0;mt<2;++mt) acc[mt] = (f32x4){0.f,0.f,0.f,0.f};
#pragma unroll
  for (int kq=0;kq<4;++kq) {
    short8 bfr = *(const short8*)&W[(ot*16+mrow)*C_ + kq*32 + quad*8];
#pragma unroll
    for (int mt=0;mt<2;++mt) acc[mt] = MFMA_BF16(am[mt][kq], bfr, acc[mt]);
  }
#pragma unroll
  for (int mt=0;mt<2;++mt)
#pragma unroll
    for (int r=0;r<4;++r)
      ys[mt*16 + quad*4 + r][ot*16 + mrow] = f2b(acc[mt][r]);
}

__device__ __forceinline__ void tile_store32_512(bf16* __restrict__ dst,
                                                 const bf16 (*ys)[136], int tid)
{
  int flat = tid*8;                                // 512 thr * 8 = 4096 = 32*128
  int p = flat >> 7, c = flat & 127;
  *(short8*)&dst[(size_t)p*C_ + c] = *(const short8*)&ys[p][c];
}

// ---------- FUSED proj + knn, 28.7KB LDS union (R1-exact: proven ~58us) ----------
// blk%5==4 -> proj block (1024, 32-pt tiles); else knn block (4096).
// R1-R4 established: knn is jointly VALU+LDS-pipe bound at occ>=36%;
// VGPR must stay <=64 (R2/R3 cliff). One point per wave, VGPR 48. FROZEN.
__global__ __launch_bounds__(512) void projknn_kernel(
    const void* __restrict__ x, const int* __restrict__ flag,
    const bf16* __restrict__ wqb, const bf16* __restrict__ wkb, const bf16* __restrict__ wvb,
    bf16* __restrict__ xTb, bf16* QT, bf16* __restrict__ KT, bf16* __restrict__ VT,
    int* __restrict__ idxout)
{
  __shared__ __align__(16) char smem[28672];       // union: knn 28672 | proj 26112
  int tid = threadIdx.x;
  int blk = blockIdx.x;
  int g = blk / 5, r = blk - g*5;
  if (r == 4) {
    // ================= proj block g ∈ [0,1024), 32 points =================
    bf16 (*xs )[136] = (bf16(*)[136])(smem);           // 8704 B (reused as ysQ)
    bf16 (*ysK)[136] = (bf16(*)[136])(smem + 8704);
    bf16 (*ysV)[136] = (bf16(*)[136])(smem + 17408);
    int p0 = g * 32;
    int b = p0 >> 14; int tn0 = p0 & (TN-1);
    if (*flag) {                                   // f32 inputs
      const float* xbase = (const float*)x + (size_t)b*C_*TN + tn0;
#pragma unroll
      for (int it=0; it<8; ++it) {
        int i = it*512 + tid;
        int c = i >> 5, p = i & 31;                // coalesced over n (128B rows)
        xs[p][c] = f2b(xbase[(size_t)c*TN + p]);
      }
    } else {                                       // bf16 inputs (bit-exact stage)
      const bf16* xbase = (const bf16*)x + (size_t)b*C_*TN + tn0;
#pragma unroll
      for (int it=0; it<8; ++it) {
        int i = it*512 + tid;
        int c = i >> 5, p = i & 31;
        xs[p][c] = xbase[(size_t)c*TN + p];
      }
    }
    __syncthreads();
    tile_store32_512(xTb + (size_t)p0*C_, xs, tid);    // point-major bf16 x
    int lane = tid & 63, wave = tid >> 6;          // 8 waves, wave = otile
    int mrow = lane & 15, quad = lane >> 4;
    short8 am[2][4];                               // A-frags (32 points = 2 mtiles)
#pragma unroll
    for (int mt=0;mt<2;++mt)
#pragma unroll
      for (int kq=0;kq<4;++kq)
        am[mt][kq] = *(const short8*)&xs[mt*16 + mrow][kq*32 + quad*8];
    __syncthreads();                               // xs reads done; xs becomes ysQ
    proj_gemm32(wqb, xs,  am, mrow, quad, wave);
    proj_gemm32(wkb, ysK, am, mrow, quad, wave);
    proj_gemm32(wvb, ysV, am, mrow, quad, wave);
    __syncthreads();
    tile_store32_512(QT + (size_t)p0*C_, xs,  tid);
    tile_store32_512(KT + (size_t)p0*C_, ysK, tid);
    tile_store32_512(VT + (size_t)p0*C_, ysV, tid);
  } else {
    // ================= knn block kblk = g*4+r ∈ [0,4096) =================
    float4* cand4 = (float4*)smem;                 // 24576 B
    u64 (*surv)[64] = (u64(*)[64])(smem + 24576);  // 4096 B
    int kblk = g*4 + r;
    int row = kblk >> 6;                           // (b,t)
    int b = row >> 5, t = row & 31;
    int ng = kblk & 63;
    bool f32 = (*flag != 0);
#pragma unroll
    for (int q = 0; q < 3; ++q) {                  // j=q time slot; 512 cols coalesced
      int tt = t - 1 + q; tt = tt < 0 ? 0 : (tt > T_-1 ? T_-1 : tt);
      size_t base = ((size_t)b*C_*T_ + tt)*(size_t)N_ + tid;   // ch0
      float c0, c1, c2;
      if (f32) {
        const float* xp = (const float*)x;
        c0 = xp[base]; c1 = xp[base + (size_t)T_*N_]; c2 = xp[base + 2*(size_t)T_*N_];
      } else {
        const bf16* xp = (const bf16*)x;
        c0 = b2f(xp[base]); c1 = b2f(xp[base + (size_t)T_*N_]); c2 = b2f(xp[base + 2*(size_t)T_*N_]);
      }
      cand4[q*N_ + tid] = make_float4(c0, c1, c2, 0.f);
    }
    __syncthreads();
    int wave = tid >> 6, lane = tid & 63;
    int n = ng*8 + wave;                           // this wave's point
    float4 a = cand4[N_ + n];                      // self (j=1 slot), broadcast read
    unsigned db[24];                               // lane owns m = lane + 64j
#pragma unroll
    for (int j = 0; j < 24; ++j) {
      float4 cm = cand4[lane + (j << 6)];          // one ds_read_b128, conflict-free
      float dx = a.x - cm.x;
      float dy = a.y - cm.y;
      float dz = a.z - cm.z;
      float d2 = __fadd_rn(__fadd_rn(__fmul_rn(dx,dx), __fmul_rn(dy,dy)), __fmul_rn(dz,dz));
      db[j] = __float_as_uint(d2);                 // d2>=0 -> u32 order == f32 order
    }
    // lane-min via pairwise tree (depth ~6, pure VALU)
    unsigned mm[12];
#pragma unroll
    for (int j = 0; j < 12; ++j) mm[j] = db[2*j] < db[2*j+1] ? db[2*j] : db[2*j+1];
#pragma unroll
    for (int j = 0; j < 6; ++j)  mm[j] = mm[2*j] < mm[2*j+1] ? mm[2*j] : mm[2*j+1];
#pragma unroll
    for (int j = 0; j < 3; ++j)  mm[j] = mm[2*j] < mm[2*j+1] ? mm[2*j] : mm[2*j+1];
    unsigned bd = mm[0] < mm[1] ? mm[0] : mm[1];
    bd = bd < mm[2] ? bd : mm[2];
    // threshold U >= exact 16th-smallest lane-min, via 16-step ballot binary
    // search on the (monotone) f32 bit pattern; invariant cnt(bd<=hi)>=16.
    {
      unsigned lo = 0u, hi = 0x7f800000u;
#pragma unroll
      for (int it = 0; it < 16; ++it) {
        unsigned mid = lo + ((hi - lo) >> 1);
        int cge = __popcll(__ballot(bd <= mid));
        bool ge = (cge >= K_);
        hi = ge ? mid : hi;
        lo = ge ? lo : (mid + 1u);
      }
      bd = hi;                                     // reuse reg: bd := U
    }
    unsigned U = bd;
    int c = 0;
#pragma unroll
    for (int j = 0; j < 24; ++j) c += (db[j] <= U) ? 1 : 0;
    // exclusive prefix (ofs) + total via 5 bit-plane ballots + mbcnt (no LDS pipe)
    int ofs = 0, total = 0;
#pragma unroll
    for (int bit = 0; bit < 5; ++bit) {
      u64 mball = __ballot(((c >> bit) & 1) != 0);
      unsigned below = __builtin_amdgcn_mbcnt_hi((unsigned)(mball >> 32),
                        __builtin_amdgcn_mbcnt_lo((unsigned)mball, 0u));
      ofs   += ((int)below) << bit;
      total += (__popcll(mball)) << bit;
    }
    int point = (b*T_ + t)*N_ + n;
    if (total <= 64) {                             // ~always (E[total] ~ 18-20)
      // compact survivors as 42-bit keys (d2<<11)|s -- same (d2,s) lex order
      // as the old (d2<<32)|s bitonic, s = lane + 64j < 2048.
#pragma unroll
      for (int j = 0; j < 24; ++j) {
        if (db[j] <= U) {
          surv[wave][ofs] = ((u64)db[j] << 11) | (unsigned)(lane + (j << 6));
          ++ofs;
        }
      }
      if (lane == total) surv[wave][lane] = ~0ull; // pad for odd-total b128 read
      __threadfence_block();
      u64 kk = (lane < total) ? surv[wave][lane] : ~0ull;
      // exact rank among survivors via broadcast LDS reads (conflict-free)
      int npair = (total + 1) >> 1;
      int rank = 0;
      const ulonglong2* sk2 = (const ulonglong2*)&surv[wave][0];
#pragma unroll 4
      for (int i2 = 0; i2 < npair; ++i2) {
        ulonglong2 kp = sk2[i2];
        rank += (kp.x < kk) ? 1 : 0;
        rank += (kp.y < kk) ? 1 : 0;
      }
      if (rank < K_) idxout[point*K_ + rank] = (int)(kk & 2047u);
    } else {
      u64 key[24];                                 // exact fallback (rare)
#pragma unroll
      for (int j = 0; j < 24; ++j)
        key[j] = ((u64)db[j] << 32) | (unsigned)(lane + (j << 6));
      u64 res = ~0ull;
#pragma unroll 1
      for (int rr = 0; rr < 16; ++rr) {
        u64 m2 = key[0];
#pragma unroll
        for (int j = 1; j < 24; ++j) m2 = (key[j] < m2) ? key[j] : m2;
#pragma unroll
        for (int s = 32; s >= 1; s >>= 1) {
          u64 p = shflx64(m2, s);
          m2 = (p < m2) ? p : m2;
        }
        if (lane == rr) res = m2;
        int mwin = (int)(m2 & 0xffffffffu);
        int sel = ((mwin & 63) == lane) ? (mwin >> 6) : -1;
#pragma unroll
        for (int j = 0; j < 24; ++j) if (j == sel) key[j] = ~0ull;
      }
      if (lane < K_) idxout[point*K_ + lane] = (int)(res & 0xffffffffu);
    }
  }
}

// ---------- R8: FUSED attention + MLP, 16 points / 256-thread block ----------
// R7 showed attnmlp latency-bound with a 4 blocks/CU grid ceiling (grid 1024
// = 16 waves/CU max, obs 37.8%). Halving block granularity -> grid 2048 =
// 8 blocks/CU x 4 waves = 32 waves/CU ceiling, LDS 14.7KB permits it.
// attn: 8 sub-iters of the identical 2-point structure; mlp: same 4-wave
// layout with the mtile dim dropped (16-pt tile = 1 mtile). Bit-identical.
__global__ __launch_bounds__(256) void attnmlp_kernel(
    const int* __restrict__ idxin, const bf16* __restrict__ xTb,
    const bf16* __restrict__ QT, const bf16* __restrict__ KT,
    const bf16* __restrict__ VT,
    const float* __restrict__ gf, const float* __restrict__ bf_,
    const float* __restrict__ mf, const float* __restrict__ vf,
    const bf16* __restrict__ w1b, const bf16* __restrict__ w2b,
    const void* __restrict__ x, const int* __restrict__ flag,
    void* __restrict__ out)
{
  __shared__ __align__(16) char smem[14848];
  bf16  (*hTl)[136]      = (bf16 (*)[136])     (smem);          // 4352 B, whole kernel
  float (*qbuf)[C_]      = (float(*)[C_])      (smem + 4352);   // 1024 B  (attn)
  int   (*col_lds)[K_]   = (int  (*)[K_])      (smem + 5376);   // 128 B   (attn)
  float (*e_lds)[4][K_]  = (float(*)[4][K_])   (smem + 5504);   // 512 B   (attn)
  bf16  (*vbuf)[K_][136] = (bf16 (*)[K_][136]) (smem + 6016);   // 8704 B  (attn)
  bf16  (*hidh)[264]     = (bf16 (*)[264])     (smem + 4352);   // 8448 B  (mlp)

  int tid = threadIdx.x;
  int gblk = (blockIdx.x & 7)*256 + (blockIdx.x >> 3);   // XCD-contiguous chunks
  int p0 = gblk * 16;
  int bb = p0 >> 14;                               // block never straddles b
  int tn0 = p0 & (TN-1);
  bool f32o = (*flag != 0);
  if (tid < 64) {                                  // passthrough ch 0..3 (bit copy)
    int c = tid >> 4, p = tid & 15;
    size_t si = ((size_t)bb*C_ + c)*TN + tn0 + p;
    size_t di = ((size_t)bb*132 + c)*TN + tn0 + p;
    if (f32o) ((float*)out)[di] = ((const float*)x)[si];
    else      ((bf16*)out)[di]  = ((const bf16*)x)[si];
  }

  // ======================= attention phase =======================
  int pt = tid >> 7, o = tid & 127;                // 2 points x 128 channels
  float sc = gf[o] / sqrtf(vf[o] + 1e-5f);
  float smean = mf[o], sbeta = bf_[o];
  float vselfC, xselfC;
  {                                                // (a_0)
    int point = p0 + pt;
    int b = point >> 14, tn = point & (TN-1), t = tn >> 9;
    if (o < K_) {
      int m = idxin[point*K_ + o];
      int j = m >> 9, nn = m & (N_-1);
      int tt = t-1+j; tt = tt<0?0:(tt>T_-1?T_-1:tt);
      col_lds[pt][o] = ((b*T_ + tt)*N_ + nn)*C_;
    }
    int self = point*C_;
    vselfC = b2f(VT[self + o]);
    xselfC = b2f(xTb[self + o]);
    qbuf[pt][o] = b2f(QT[self + o]);
  }
  __syncthreads();
#pragma unroll 1
  for (int sub = 0; sub < 8; ++sub) {
    {                                              // (c) fused gather + energy
      int k = o >> 3, c = o & 7, hd = c >> 1;
      int src = col_lds[pt][k] + c*16;
      short8 kv0 = *(const short8*)&KT[src];
      short8 kv1 = *(const short8*)&KT[src + 8];
      short8 vv0 = *(const short8*)&VT[src];
      short8 vv1 = *(const short8*)&VT[src + 8];
      *(short8*)&vbuf[pt][k][c*16]     = vv0;
      *(short8*)&vbuf[pt][k][c*16 + 8] = vv1;
      const float* qp = &qbuf[pt][c*16];           // == hd*32 + (c&1)*16
      float qv[16];
      *(float4*)&qv[0]  = *(const float4*)(qp);
      *(float4*)&qv[4]  = *(const float4*)(qp + 4);
      *(float4*)&qv[8]  = *(const float4*)(qp + 8);
      *(float4*)&qv[12] = *(const float4*)(qp + 12);
      float e = 0.f;
#pragma unroll
      for (int i2=0;i2<8;++i2) e = fmaf(qv[i2],   bqf(kv0[i2]), e);
#pragma unroll
      for (int i2=0;i2<8;++i2) e = fmaf(qv[8+i2], bqf(kv1[i2]), e);
      e += __shfl_xor(e, 1, 64);                   // combine the (c&1) pair
      // energy = q.(Kself - Knb)/sqrt(D); self term k-constant -> dropped
      if (!(c & 1)) e_lds[pt][hd][k] = -e * 0.17677669529663687f;
    }
    __syncthreads();
    {                                              // (d) softmax + agg + bn -> hTl
      int hd = o >> 5;
      float e[16]; float mx = -3e38f;
#pragma unroll
      for (int k=0;k<K_;++k){ e[k]=e_lds[pt][hd][k]; mx=fmaxf(mx,e[k]); }
      float ssum=0.f;
#pragma unroll
      for (int k=0;k<K_;++k){ e[k]=__expf(e[k]-mx); ssum+=e[k]; }
      float inv = 1.f/ssum;
      float acc = vselfC;                          // agg = Vself - sum attn*Vnb
#pragma unroll
      for (int k=0;k<K_;++k)
        acc = fmaf(-(e[k]*inv), b2f(vbuf[pt][k][o]), acc);
      float hv = xselfC + acc;
      hTl[sub*2 + pt][o] = f2b((hv - smean)*sc + sbeta);
    }
    if (sub < 7) {                                 // (a_{s+1}) prefetch next pair
      int point = p0 + (sub+1)*2 + pt;
      int b = point >> 14, tn = point & (TN-1), t = tn >> 9;
      if (o < K_) {
        int m = idxin[point*K_ + o];
        int j = m >> 9, nn = m & (N_-1);
        int tt = t-1+j; tt = tt<0?0:(tt>T_-1?T_-1:tt);
        col_lds[pt][o] = ((b*T_ + tt)*N_ + nn)*C_;
      }
      int self = point*C_;
      vselfC = b2f(VT[self + o]);
      xselfC = b2f(xTb[self + o]);
      qbuf[pt][o] = b2f(QT[self + o]);
    }
    __syncthreads();
  }

  // ======================= MLP phase (4-wave, 16-pt tile = 1 mtile) =======================
  int lane = tid & 63, wave = tid >> 6;
  int mrow = lane & 15, quad = lane >> 4;
  f32x4 acc2[2];                                   // [otile], persists both halves
#pragma unroll
  for (int oi=0;oi<2;++oi) acc2[oi] = (f32x4){0.f,0.f,0.f,0.f};

#pragma unroll
  for (int half = 0; half < 2; ++half) {
    if (half) __syncthreads();                     // prev stage2 reads done
    short8 am[4];                                  // A-frags from LDS hT tile
#pragma unroll
    for (int kq=0;kq<4;++kq)
      am[kq] = *(const short8*)&hTl[mrow][kq*32 + quad*8];
#pragma unroll
    for (int oi = 0; oi < 4; ++oi) {               // wave owns 4 of this half's 16 otiles
      int ot_g = half*16 + wave*4 + oi;
      int otl  = wave*4 + oi;
      f32x4 acc = (f32x4){0.f,0.f,0.f,0.f};
#pragma unroll
      for (int kq=0;kq<4;++kq) {
        short8 bfr = *(const short8*)&w1b[(ot_g*16+mrow)*C_ + kq*32 + quad*8];
        acc = MFMA_BF16(am[kq], bfr, acc);
      }
#pragma unroll
      for (int r=0;r<4;++r) {
        float z = acc[r];
        hidh[quad*4 + r][otl*16 + mrow] = f2b(z > 0.f ? z : 0.2f*z);
      }
    }
    __syncthreads();
#pragma unroll
    for (int kc = 0; kc < 4; ++kc) {               // 4 chunks of 2 k-slices
      short8 ha[2];
#pragma unroll
      for (int kk=0;kk<2;++kk)
        ha[kk] = *(const short8*)&hidh[mrow][(kc*2+kk)*32 + quad*8];
#pragma unroll
      for (int oi=0;oi<2;++oi) {
        int ot2 = wave*2 + oi;                     // wave owns 2 of 8 output otiles
#pragma unroll
        for (int kk=0;kk<2;++kk) {
          int ks_g = half*8 + kc*2 + kk;
          short8 bfr = *(const short8*)&w2b[(ot2*16+mrow)*HID_ + ks_g*32 + quad*8];
          acc2[oi] = MFMA_BF16(ha[kk], bfr, acc2[oi]);
        }
      }
    }
  }
  size_t obase = (size_t)bb*132*TN;
#pragma unroll
  for (int oi=0;oi<2;++oi) {
    int ch = (wave*2+oi)*16 + mrow;
    int tn = tn0 + quad*4;
    size_t oidx = obase + (size_t)(4+ch)*TN + tn;
    if (f32o) {
      *(f32x4*)&((float*)out)[oidx] = acc2[oi];
    } else {
      bf16 tmp[4];
#pragma unroll
      for (int r=0;r<4;++r) tmp[r] = f2b(acc2[oi][r]);
      *(u64*)&((bf16*)out)[oidx] = *(u64*)tmp;
    }
  }
}

extern "C" void kernel_launch(void* const* d_in, const int* in_sizes, int n_in,
                              void* d_out, int out_size, void* d_ws, size_t ws_size,
                              hipStream_t stream)
{
  (void)in_sizes; (void)n_in; (void)out_size; (void)ws_size;
  const void* x = d_in[0];
  char* ws = (char*)d_ws;
  const size_t MB = (size_t)1<<20;
  bf16*  QT  = (bf16* )(ws + 0*MB);      // 8 MB
  bf16*  KT  = (bf16* )(ws + 8*MB);      // 8 MB
  bf16*  VT  = (bf16* )(ws + 16*MB);     // 8 MB
  bf16*  xTb = (bf16* )(ws + 24*MB);     // 8 MB
  int*   idxw= (int*  )(ws + 32*MB);     // 2 MB
  bf16*  wqb = (bf16* )(ws + 34*MB);             // 32 KB
  bf16*  wkb = (bf16* )(ws + 34*MB + 0x8000);    // 32 KB
  bf16*  wvb = (bf16* )(ws + 34*MB + 0x10000);   // 32 KB
  bf16*  w1b = (bf16* )(ws + 34*MB + 0x18000);   // 128 KB
  bf16*  w2b = (bf16* )(ws + 34*MB + 0x38000);   // 128 KB
  float* gf  = (float*)(ws + 34*MB + 0x58000);
  float* bf_ = (float*)(ws + 34*MB + 0x58200);
  float* mf  = (float*)(ws + 34*MB + 0x58400);
  float* vf  = (float*)(ws + 34*MB + 0x58600);
  int*  flag = (int*  )(ws + 34*MB + 0x58800);

  convw_kernel  <<<dim3(706), dim3(256), 0, stream>>>(
      x, d_in[1], d_in[2], d_in[3], d_in[4], d_in[5],
      d_in[6], d_in[7], d_in[8], d_in[9],
      wqb, wkb, wvb, w1b, w2b, gf, bf_, mf, vf, flag);
  projknn_kernel<<<dim3(5120), dim3(512), 0, stream>>>(
      x, flag, wqb, wkb, wvb, xTb, QT, KT, VT, idxw);
  attnmlp_kernel<<<dim3(PTS/16), dim3(256), 0, stream>>>(
      idxw, xTb, QT, KT, VT, gf, bf_, mf, vf, w1b, w2b, x, flag, d_out);
}

// Round 9
// 190.072 us; speedup vs baseline: 1.1719x; 1.1719x over previous
//
#include <hip/hip_runtime.h>
#include <hip/hip_bf16.h>

typedef __hip_bfloat16 bf16;
typedef unsigned long long u64;
typedef __attribute__((ext_vector_type(8))) short short8;   // 8 bf16 = MFMA A/B frag
typedef __attribute__((ext_vector_type(4))) float f32x4;    // MFMA C/D frag

#define B_   2
#define C_   128
#define T_   32
#define N_   512
#define K_   16
#define HID_ 512
#define TN   (T_*N_)          // 16384
#define PTS  (B_*T_*N_)       // 32768

#define MFMA_BF16(a,b,c) __builtin_amdgcn_mfma_f32_16x16x32_bf16((a),(b),(c),0,0,0)

__device__ __forceinline__ float b2f(bf16 v){ return __bfloat162float(v); }
__device__ __forceinline__ bf16  f2b(float v){ return __float2bfloat16(v); }
__device__ __forceinline__ float bqf(short v){            // bf16 bits -> f32 (exact)
  return __uint_as_float(((unsigned)(unsigned short)v) << 16);
}

__device__ __forceinline__ float ldc(const void* p, int i, bool f32) {
  return f32 ? ((const float*)p)[i] : b2f(((const bf16*)p)[i]);
}

// ---------- convert weights + bn; every block locally detects input dtype; blk0 publishes flag ----------
__global__ __launch_bounds__(256) void convw_kernel(
    const void* __restrict__ x,
    const void* wq, const void* wk, const void* wv,
    const void* w1, const void* w2, const void* g, const void* bb,
    const void* m, const void* v,
    bf16* __restrict__ wqb, bf16* __restrict__ wkb, bf16* __restrict__ wvb,
    bf16* __restrict__ w1b, bf16* __restrict__ w2b,
    float* __restrict__ gf, float* __restrict__ bf_, float* __restrict__ mf,
    float* __restrict__ vf, int* __restrict__ flag)
{
  __shared__ int cnt;
  if (threadIdx.x == 0) cnt = 0;
  __syncthreads();
  const unsigned short* u = (const unsigned short*)x;
  int w = 0;
#pragma unroll
  for (int j = 0; j < 8; ++j) {
    unsigned short hv = u[threadIdx.x*8 + j];
    int e = (hv >> 7) & 0xFF;
    if (e >= 0x89) w++;
  }
  if (w) atomicAdd(&cnt, w);
  __syncthreads();
  bool f32 = (cnt > 32);
  if (blockIdx.x == 0 && threadIdx.x == 0) *flag = f32 ? 1 : 0;

  int i = blockIdx.x*256 + threadIdx.x;            // grid covers 180736 exactly
  if (i < 16384) { wqb[i] = f2b(ldc(wq, i, f32)); return; } i -= 16384;
  if (i < 16384) { wkb[i] = f2b(ldc(wk, i, f32)); return; } i -= 16384;
  if (i < 16384) { wvb[i] = f2b(ldc(wv, i, f32)); return; } i -= 16384;
  if (i < 65536) { w1b[i] = f2b(ldc(w1, i, f32)); return; } i -= 65536;
  if (i < 65536) { w2b[i] = f2b(ldc(w2, i, f32)); return; } i -= 65536;
  if (i < 128)   { gf[i]  = ldc(g, i, f32); return; }       i -= 128;
  if (i < 128)   { bf_[i] = ldc(bb, i, f32); return; }      i -= 128;
  if (i < 128)   { mf[i]  = ldc(m, i, f32); return; }       i -= 128;
  if (i < 128)   { vf[i]  = ldc(v, i, f32); return; }
}

// ---------- bitonic/shuffle helpers ----------
__device__ __forceinline__ u64 shflx64(u64 v, int m) {
  return (u64)__shfl_xor((long long)v, m, 64);
}

// ---------- MFMA GEMM helper (32-pt tile, 8 waves, wave owns one 16-col otile) ----------
__device__ __forceinline__ void proj_gemm32(const bf16* __restrict__ W,
                                            bf16 (*ys)[136],
                                            const short8 am[2][4],
                                            int mrow, int quad, int ot)
{
  f32x4 acc[2];
#pragma unroll
  for (int mt=0;mt<2;++mt) acc[mt] = (f32x4){0.f,0.f,0.f,0.f};
#pragma unroll
  for (int kq=0;kq<4;++kq) {
    short8 bfr = *(const short8*)&W[(ot*16+mrow)*C_ + kq*32 + quad*8];
#pragma unroll
    for (int mt=0;mt<2;++mt) acc[mt] = MFMA_BF16(am[mt][kq], bfr, acc[mt]);
  }
#pragma unroll
  for (int mt=0;mt<2;++mt)
#pragma unroll
    for (int r=0;r<4;++r)
      ys[mt*16 + quad*4 + r][ot*16 + mrow] = f2b(acc[mt][r]);
}

__device__ __forceinline__ void tile_store32_512(bf16* __restrict__ dst,
                                                 const bf16 (*ys)[136], int tid)
{
  int flat = tid*8;                                // 512 thr * 8 = 4096 = 32*128
  int p = flat >> 7, c = flat & 127;
  *(short8*)&dst[(size_t)p*C_ + c] = *(const short8*)&ys[p][c];
}

// ---------- FUSED proj + knn, 28.7KB LDS union (R1-exact: proven ~58us) ----------
// blk%5==4 -> proj block (1024, 32-pt tiles); else knn block (4096).
// R1-R4 established: knn is jointly VALU+LDS-pipe bound at occ>=36%;
// VGPR must stay <=64 (R2/R3 cliff). One point per wave, VGPR 48. FROZEN.
__global__ __launch_bounds__(512) void projknn_kernel(
    const void* __restrict__ x, const int* __restrict__ flag,
    const bf16* __restrict__ wqb, const bf16* __restrict__ wkb, const bf16* __restrict__ wvb,
    bf16* __restrict__ xTb, bf16* QT, bf16* __restrict__ KT, bf16* __restrict__ VT,
    int* __restrict__ idxout)
{
  __shared__ __align__(16) char smem[28672];       // union: knn 28672 | proj 26112
  int tid = threadIdx.x;
  int blk = blockIdx.x;
  int g = blk / 5, r = blk - g*5;
  if (r == 4) {
    // ================= proj block g ∈ [0,1024), 32 points =================
    bf16 (*xs )[136] = (bf16(*)[136])(smem);           // 8704 B (reused as ysQ)
    bf16 (*ysK)[136] = (bf16(*)[136])(smem + 8704);
    bf16 (*ysV)[136] = (bf16(*)[136])(smem + 17408);
    int p0 = g * 32;
    int b = p0 >> 14; int tn0 = p0 & (TN-1);
    if (*flag) {                                   // f32 inputs
      const float* xbase = (const float*)x + (size_t)b*C_*TN + tn0;
#pragma unroll
      for (int it=0; it<8; ++it) {
        int i = it*512 + tid;
        int c = i >> 5, p = i & 31;                // coalesced over n (128B rows)
        xs[p][c] = f2b(xbase[(size_t)c*TN + p]);
      }
    } else {                                       // bf16 inputs (bit-exact stage)
      const bf16* xbase = (const bf16*)x + (size_t)b*C_*TN + tn0;
#pragma unroll
      for (int it=0; it<8; ++it) {
        int i = it*512 + tid;
        int c = i >> 5, p = i & 31;
        xs[p][c] = xbase[(size_t)c*TN + p];
      }
    }
    __syncthreads();
    tile_store32_512(xTb + (size_t)p0*C_, xs, tid);    // point-major bf16 x
    int lane = tid & 63, wave = tid >> 6;          // 8 waves, wave = otile
    int mrow = lane & 15, quad = lane >> 4;
    short8 am[2][4];                               // A-frags (32 points = 2 mtiles)
#pragma unroll
    for (int mt=0;mt<2;++mt)
#pragma unroll
      for (int kq=0;kq<4;++kq)
        am[mt][kq] = *(const short8*)&xs[mt*16 + mrow][kq*32 + quad*8];
    __syncthreads();                               // xs reads done; xs becomes ysQ
    proj_gemm32(wqb, xs,  am, mrow, quad, wave);
    proj_gemm32(wkb, ysK, am, mrow, quad, wave);
    proj_gemm32(wvb, ysV, am, mrow, quad, wave);
    __syncthreads();
    tile_store32_512(QT + (size_t)p0*C_, xs,  tid);
    tile_store32_512(KT + (size_t)p0*C_, ysK, tid);
    tile_store32_512(VT + (size_t)p0*C_, ysV, tid);
  } else {
    // ================= knn block kblk = g*4+r ∈ [0,4096) =================
    float4* cand4 = (float4*)smem;                 // 24576 B
    u64 (*surv)[64] = (u64(*)[64])(smem + 24576);  // 4096 B
    int kblk = g*4 + r;
    int row = kblk >> 6;                           // (b,t)
    int b = row >> 5, t = row & 31;
    int ng = kblk & 63;
    bool f32 = (*flag != 0);
#pragma unroll
    for (int q = 0; q < 3; ++q) {                  // j=q time slot; 512 cols coalesced
      int tt = t - 1 + q; tt = tt < 0 ? 0 : (tt > T_-1 ? T_-1 : tt);
      size_t base = ((size_t)b*C_*T_ + tt)*(size_t)N_ + tid;   // ch0
      float c0, c1, c2;
      if (f32) {
        const float* xp = (const float*)x;
        c0 = xp[base]; c1 = xp[base + (size_t)T_*N_]; c2 = xp[base + 2*(size_t)T_*N_];
      } else {
        const bf16* xp = (const bf16*)x;
        c0 = b2f(xp[base]); c1 = b2f(xp[base + (size_t)T_*N_]); c2 = b2f(xp[base + 2*(size_t)T_*N_]);
      }
      cand4[q*N_ + tid] = make_float4(c0, c1, c2, 0.f);
    }
    __syncthreads();
    int wave = tid >> 6, lane = tid & 63;
    int n = ng*8 + wave;                           // this wave's point
    float4 a = cand4[N_ + n];                      // self (j=1 slot), broadcast read
    unsigned db[24];                               // lane owns m = lane + 64j
#pragma unroll
    for (int j = 0; j < 24; ++j) {
      float4 cm = cand4[lane + (j << 6)];          // one ds_read_b128, conflict-free
      float dx = a.x - cm.x;
      float dy = a.y - cm.y;
      float dz = a.z - cm.z;
      float d2 = __fadd_rn(__fadd_rn(__fmul_rn(dx,dx), __fmul_rn(dy,dy)), __fmul_rn(dz,dz));
      db[j] = __float_as_uint(d2);                 // d2>=0 -> u32 order == f32 order
    }
    // lane-min via pairwise tree (depth ~6, pure VALU)
    unsigned mm[12];
#pragma unroll
    for (int j = 0; j < 12; ++j) mm[j] = db[2*j] < db[2*j+1] ? db[2*j] : db[2*j+1];
#pragma unroll
    for (int j = 0; j < 6; ++j)  mm[j] = mm[2*j] < mm[2*j+1] ? mm[2*j] : mm[2*j+1];
#pragma unroll
    for (int j = 0; j < 3; ++j)  mm[j] = mm[2*j] < mm[2*j+1] ? mm[2*j] : mm[2*j+1];
    unsigned bd = mm[0] < mm[1] ? mm[0] : mm[1];
    bd = bd < mm[2] ? bd : mm[2];
    // threshold U >= exact 16th-smallest lane-min, via 16-step ballot binary
    // search on the (monotone) f32 bit pattern; invariant cnt(bd<=hi)>=16.
    {
      unsigned lo = 0u, hi = 0x7f800000u;
#pragma unroll
      for (int it = 0; it < 16; ++it) {
        unsigned mid = lo + ((hi - lo) >> 1);
        int cge = __popcll(__ballot(bd <= mid));
        bool ge = (cge >= K_);
        hi = ge ? mid : hi;
        lo = ge ? lo : (mid + 1u);
      }
      bd = hi;                                     // reuse reg: bd := U
    }
    unsigned U = bd;
    int c = 0;
#pragma unroll
    for (int j = 0; j < 24; ++j) c += (db[j] <= U) ? 1 : 0;
    // exclusive prefix (ofs) + total via 5 bit-plane ballots + mbcnt (no LDS pipe)
    int ofs = 0, total = 0;
#pragma unroll
    for (int bit = 0; bit < 5; ++bit) {
      u64 mball = __ballot(((c >> bit) & 1) != 0);
      unsigned below = __builtin_amdgcn_mbcnt_hi((unsigned)(mball >> 32),
                        __builtin_amdgcn_mbcnt_lo((unsigned)mball, 0u));
      ofs   += ((int)below) << bit;
      total += (__popcll(mball)) << bit;
    }
    int point = (b*T_ + t)*N_ + n;
    if (total <= 64) {                             // ~always (E[total] ~ 18-20)
      // compact survivors as 42-bit keys (d2<<11)|s -- same (d2,s) lex order
      // as the old (d2<<32)|s bitonic, s = lane + 64j < 2048.
#pragma unroll
      for (int j = 0; j < 24; ++j) {
        if (db[j] <= U) {
          surv[wave][ofs] = ((u64)db[j] << 11) | (unsigned)(lane + (j << 6));
          ++ofs;
        }
      }
      if (lane == total) surv[wave][lane] = ~0ull; // pad for odd-total b128 read
      __threadfence_block();
      u64 kk = (lane < total) ? surv[wave][lane] : ~0ull;
      // exact rank among survivors via broadcast LDS reads (conflict-free)
      int npair = (total + 1) >> 1;
      int rank = 0;
      const ulonglong2* sk2 = (const ulonglong2*)&surv[wave][0];
#pragma unroll 4
      for (int i2 = 0; i2 < npair; ++i2) {
        ulonglong2 kp = sk2[i2];
        rank += (kp.x < kk) ? 1 : 0;
        rank += (kp.y < kk) ? 1 : 0;
      }
      if (rank < K_) idxout[point*K_ + rank] = (int)(kk & 2047u);
    } else {
      u64 key[24];                                 // exact fallback (rare)
#pragma unroll
      for (int j = 0; j < 24; ++j)
        key[j] = ((u64)db[j] << 32) | (unsigned)(lane + (j << 6));
      u64 res = ~0ull;
#pragma unroll 1
      for (int rr = 0; rr < 16; ++rr) {
        u64 m2 = key[0];
#pragma unroll
        for (int j = 1; j < 24; ++j) m2 = (key[j] < m2) ? key[j] : m2;
#pragma unroll
        for (int s = 32; s >= 1; s >>= 1) {
          u64 p = shflx64(m2, s);
          m2 = (p < m2) ? p : m2;
        }
        if (lane == rr) res = m2;
        int mwin = (int)(m2 & 0xffffffffu);
        int sel = ((mwin & 63) == lane) ? (mwin >> 6) : -1;
#pragma unroll
        for (int j = 0; j < 24; ++j) if (j == sel) key[j] = ~0ull;
      }
      if (lane < K_) idxout[point*K_ + lane] = (int)(res & 0xffffffffu);
    }
  }
}

// ---------- R9: FUSED attention + MLP, 32 pts / 256 thr (R7 base) ----------
// R8 refuted the TLP theory (occupancy flat at 2x grid). Binder = per-sub
// serial gather latency: K/V loads issued and consumed within one sub-iter.
// R9 pipelines one sub deep: (1) ALL 512 gather col addresses precomputed
// once into LDS colbuf (idx loads + addr math leave the loop); (2) K/V for
// sub s held in regs; loads for s+1 issued during s's energy phase, drain
// across 2 barriers + softmax before use; (3) qbuf double-buffered so Q/self
// prefetch overlaps too. Same fmaf order/operands -> bit-identical output.
__global__ __launch_bounds__(256) void attnmlp_kernel(
    const int* __restrict__ idxin, const bf16* __restrict__ xTb,
    const bf16* __restrict__ QT, const bf16* __restrict__ KT,
    const bf16* __restrict__ VT,
    const float* __restrict__ gf, const float* __restrict__ bf_,
    const float* __restrict__ mf, const float* __restrict__ vf,
    const bf16* __restrict__ w1b, const bf16* __restrict__ w2b,
    const void* __restrict__ x, const int* __restrict__ flag,
    void* __restrict__ out)
{
  __shared__ __align__(16) char smem[25600];
  bf16  (*hTl)[136]       = (bf16 (*)[136])      (smem);          // 8704 B, whole kernel
  int   (*colbuf)[K_]     = (int  (*)[K_])       (smem + 8704);   // 2048 B (attn)
  float (*qbuf)[2][C_]    = (float(*)[2][C_])    (smem + 10752);  // 2048 B (attn, dbuf)
  float (*e_lds)[4][K_]   = (float(*)[4][K_])    (smem + 12800);  // 512 B  (attn)
  bf16  (*vbuf)[K_][136]  = (bf16 (*)[K_][136])  (smem + 13312);  // 8704 B (attn)
  bf16  (*hidh)[264]      = (bf16 (*)[264])      (smem + 8704);   // 16896 B (mlp)

  int tid = threadIdx.x;
  int gblk = (blockIdx.x & 7)*128 + (blockIdx.x >> 3);   // XCD-contiguous chunks
  int p0 = gblk * 32;
  int bb = p0 >> 14;                               // block never straddles b
  int tn0 = p0 & (TN-1);
  bool f32o = (*flag != 0);
  if (tid < 128) {                                 // passthrough ch 0..3 (bit copy)
    int c = tid >> 5, p = tid & 31;
    size_t si = ((size_t)bb*C_ + c)*TN + tn0 + p;
    size_t di = ((size_t)bb*132 + c)*TN + tn0 + p;
    if (f32o) ((float*)out)[di] = ((const float*)x)[si];
    else      ((bf16*)out)[di]  = ((const bf16*)x)[si];
  }

  // ======================= attention phase =======================
  // t is constant across the block's 32 points (tn0 multiple of 32;
  // tn0 mod 512 <= 480 so tn0+31 never crosses a 512 boundary).
  int tblk = tn0 >> 9;
  // ---- precompute all 512 gather columns: 2 entries/thread ----
#pragma unroll
  for (int it = 0; it < 2; ++it) {
    int e = it*256 + tid;
    int row = e >> 4, kk = e & 15;                 // row = local point 0..31
    int m = idxin[(p0 + row)*K_ + kk];
    int j = m >> 9, nn = m & (N_-1);
    int tt = tblk-1+j; tt = tt<0?0:(tt>T_-1?T_-1:tt);
    colbuf[row][kk] = ((bb*T_ + tt)*N_ + nn)*C_;
  }

  int pt = tid >> 7, o = tid & 127;                // 2 points / sub x 128 channels
  int k = o >> 3, c = o & 7, hd = c >> 1;
  float sc = gf[o] / sqrtf(vf[o] + 1e-5f);
  float smean = mf[o], sbeta = bf_[o];
  float vselfC, xselfC, vselfN = 0.f, xselfN = 0.f;
  {                                                // prologue: sub-0 Q/self
    int self = (p0 + pt)*C_;
    vselfC = b2f(VT[self + o]);
    xselfC = b2f(xTb[self + o]);
    qbuf[0][pt][o] = b2f(QT[self + o]);
  }
  __syncthreads();                                 // colbuf + qbuf[0] ready
  short8 kv0, kv1, vv0, vv1;
  {                                                // prologue: sub-0 K/V regs
    int src = colbuf[pt][k] + c*16;
    kv0 = *(const short8*)&KT[src];
    kv1 = *(const short8*)&KT[src + 8];
    vv0 = *(const short8*)&VT[src];
    vv1 = *(const short8*)&VT[src + 8];
  }
#pragma unroll 1
  for (int sub = 0; sub < 16; ++sub) {
    int cur = sub & 1, nxt = cur ^ 1;
    {                                              // (c) consume regs: vbuf + energy
      *(short8*)&vbuf[pt][k][c*16]     = vv0;
      *(short8*)&vbuf[pt][k][c*16 + 8] = vv1;
      const float* qp = &qbuf[cur][pt][c*16];      // == hd*32 + (c&1)*16
      float qv[16];
      *(float4*)&qv[0]  = *(const float4*)(qp);
      *(float4*)&qv[4]  = *(const float4*)(qp + 4);
      *(float4*)&qv[8]  = *(const float4*)(qp + 8);
      *(float4*)&qv[12] = *(const float4*)(qp + 12);
      float e = 0.f;
#pragma unroll
      for (int i2=0;i2<8;++i2) e = fmaf(qv[i2],   bqf(kv0[i2]), e);
#pragma unroll
      for (int i2=0;i2<8;++i2) e = fmaf(qv[8+i2], bqf(kv1[i2]), e);
      e += __shfl_xor(e, 1, 64);                   // combine the (c&1) pair
      // energy = q.(Kself - Knb)/sqrt(D); self term k-constant -> dropped
      if (!(c & 1)) e_lds[pt][hd][k] = -e * 0.17677669529663687f;
    }
    if (sub < 15) {                                // prefetch sub+1 (drains across
      int row = (sub+1)*2 + pt;                    //  2 barriers + softmax)
      int src = colbuf[row][k] + c*16;
      kv0 = *(const short8*)&KT[src];
      kv1 = *(const short8*)&KT[src + 8];
      vv0 = *(const short8*)&VT[src];
      vv1 = *(const short8*)&VT[src + 8];
      int self = (p0 + row)*C_;
      vselfN = b2f(VT[self + o]);
      xselfN = b2f(xTb[self + o]);
      qbuf[nxt][pt][o] = b2f(QT[self + o]);
    }
    __syncthreads();
    {                                              // (d) softmax + agg + bn -> hTl
      int hd2 = o >> 5;
      float ee[16]; float mx = -3e38f;
#pragma unroll
      for (int kk=0;kk<K_;++kk){ ee[kk]=e_lds[pt][hd2][kk]; mx=fmaxf(mx,ee[kk]); }
      float ssum=0.f;
#pragma unroll
      for (int kk=0;kk<K_;++kk){ ee[kk]=__expf(ee[kk]-mx); ssum+=ee[kk]; }
      float inv = 1.f/ssum;
      float acc = vselfC;                          // agg = Vself - sum attn*Vnb
#pragma unroll
      for (int kk=0;kk<K_;++kk)
        acc = fmaf(-(ee[kk]*inv), b2f(vbuf[pt][kk][o]), acc);
      float hv = xselfC + acc;
      hTl[sub*2 + pt][o] = f2b((hv - smean)*sc + sbeta);
    }
    vselfC = vselfN; xselfC = xselfN;
    __syncthreads();
  }

  // ======================= MLP phase (R7-exact, hT from LDS) =======================
  int lane = tid & 63, wave = tid >> 6;
  int mrow = lane & 15, quad = lane >> 4;
  f32x4 acc2[2][2];                                // [otile][mtile], persists both halves
#pragma unroll
  for (int oi=0;oi<2;++oi)
#pragma unroll
    for (int mt=0;mt<2;++mt) acc2[oi][mt] = (f32x4){0.f,0.f,0.f,0.f};

#pragma unroll
  for (int half = 0; half < 2; ++half) {
    if (half) __syncthreads();                     // prev stage2 reads done
    short8 am[2][4];                               // A-frags from LDS hT tile
#pragma unroll
    for (int mt=0;mt<2;++mt)
#pragma unroll
      for (int kq=0;kq<4;++kq)
        am[mt][kq] = *(const short8*)&hTl[mt*16 + mrow][kq*32 + quad*8];
#pragma unroll
    for (int oi = 0; oi < 4; ++oi) {               // wave owns 4 of this half's 16 otiles
      int ot_g = half*16 + wave*4 + oi;
      int otl  = wave*4 + oi;
      f32x4 acc[2];
#pragma unroll
      for (int mt=0;mt<2;++mt) acc[mt] = (f32x4){0.f,0.f,0.f,0.f};
#pragma unroll
      for (int kq=0;kq<4;++kq) {
        short8 bfr = *(const short8*)&w1b[(ot_g*16+mrow)*C_ + kq*32 + quad*8];
#pragma unroll
        for (int mt=0;mt<2;++mt) acc[mt] = MFMA_BF16(am[mt][kq], bfr, acc[mt]);
      }
#pragma unroll
      for (int mt=0;mt<2;++mt)
#pragma unroll
        for (int r=0;r<4;++r) {
          float z = acc[mt][r];
          hidh[mt*16 + quad*4 + r][otl*16 + mrow] = f2b(z > 0.f ? z : 0.2f*z);
        }
    }
    __syncthreads();
#pragma unroll
    for (int kc = 0; kc < 4; ++kc) {               // 4 chunks of 2 k-slices
      short8 ha[2][2];
#pragma unroll
      for (int mt=0;mt<2;++mt)
#pragma unroll
        for (int kk=0;kk<2;++kk)
          ha[mt][kk] = *(const short8*)&hidh[mt*16 + mrow][(kc*2+kk)*32 + quad*8];
#pragma unroll
      for (int oi=0;oi<2;++oi) {
        int ot2 = wave*2 + oi;                     // wave owns 2 of 8 output otiles
#pragma unroll
        for (int kk=0;kk<2;++kk) {
          int ks_g = half*8 + kc*2 + kk;
          short8 bfr = *(const short8*)&w2b[(ot2*16+mrow)*HID_ + ks_g*32 + quad*8];
#pragma unroll
          for (int mt=0;mt<2;++mt)
            acc2[oi][mt] = MFMA_BF16(ha[mt][kk], bfr, acc2[oi][mt]);
        }
      }
    }
  }
  size_t obase = (size_t)bb*132*TN;
#pragma unroll
  for (int oi=0;oi<2;++oi) {
    int ch = (wave*2+oi)*16 + mrow;
#pragma unroll
    for (int mt=0;mt<2;++mt) {
      int tn = tn0 + mt*16 + quad*4;
      size_t oidx = obase + (size_t)(4+ch)*TN + tn;
      if (f32o) {
        *(f32x4*)&((float*)out)[oidx] = acc2[oi][mt];
      } else {
        bf16 tmp[4];
#pragma unroll
        for (int r=0;r<4;++r) tmp[r] = f2b(acc2[oi][mt][r]);
        *(u64*)&((bf16*)out)[oidx] = *(u64*)tmp;
      }
    }
  }
}

extern "C" void kernel_launch(void* const* d_in, const int* in_sizes, int n_in,
                              void* d_out, int out_size, void* d_ws, size_t ws_size,
                              hipStream_t stream)
{
  (void)in_sizes; (void)n_in; (void)out_size; (void)ws_size;
  const void* x = d_in[0];
  char* ws = (char*)d_ws;
  const size_t MB = (size_t)1<<20;
  bf16*  QT  = (bf16* )(ws + 0*MB);      // 8 MB
  bf16*  KT  = (bf16* )(ws + 8*MB);      // 8 MB
  bf16*  VT  = (bf16* )(ws + 16*MB);     // 8 MB
  bf16*  xTb = (bf16* )(ws + 24*MB);     // 8 MB
  int*   idxw= (int*  )(ws + 32*MB);     // 2 MB
  bf16*  wqb = (bf16* )(ws + 34*MB);             // 32 KB
  bf16*  wkb = (bf16* )(ws + 34*MB + 0x8000);    // 32 KB
  bf16*  wvb = (bf16* )(ws + 34*MB + 0x10000);   // 32 KB
  bf16*  w1b = (bf16* )(ws + 34*MB + 0x18000);   // 128 KB
  bf16*  w2b = (bf16* )(ws + 34*MB + 0x38000);   // 128 KB
  float* gf  = (float*)(ws + 34*MB + 0x58000);
  float* bf_ = (float*)(ws + 34*MB + 0x58200);
  float* mf  = (float*)(ws + 34*MB + 0x58400);
  float* vf  = (float*)(ws + 34*MB + 0x58600);
  int*  flag = (int*  )(ws + 34*MB + 0x58800);

  convw_kernel  <<<dim3(706), dim3(256), 0, stream>>>(
      x, d_in[1], d_in[2], d_in[3], d_in[4], d_in[5],
      d_in[6], d_in[7], d_in[8], d_in[9],
      wqb, wkb, wvb, w1b, w2b, gf, bf_, mf, vf, flag);
  projknn_kernel<<<dim3(5120), dim3(512), 0, stream>>>(
      x, flag, wqb, wkb, wvb, xTb, QT, KT, VT, idxw);
  attnmlp_kernel<<<dim3(PTS/32), dim3(256), 0, stream>>>(
      idxw, xTb, QT, KT, VT, gf, bf_, mf, vf, w1b, w2b, x, flag, d_out);
}